// Round 12
// baseline (7771.799 us; speedup 1.0000x reference)
//
#include <hip/hip_runtime.h>

// ---------------- problem constants ----------------
#define BB 256   // batch
#define TT 256   // time steps
#define II 16    // input dim (layer 0)
#define HH 512   // hidden
#define G4 2048  // 4*H
#define LL 4     // layers
#define POISON 0xFFFFFFFFu   // f16 pair = (-NaN,-NaN): unreachable for h = o*tanh(c)

typedef float f32x4 __attribute__((ext_vector_type(4)));
typedef _Float16 f16x8 __attribute__((ext_vector_type(8)));
typedef _Float16 f16x4 __attribute__((ext_vector_type(4)));
typedef float f32x4v __attribute__((ext_vector_type(4)));
typedef unsigned int u32x4 __attribute__((ext_vector_type(4)));
typedef unsigned long long u64;

#define MFMA16(a, b, c) __builtin_amdgcn_mfma_f32_16x16x32_f16((a), (b), (c), 0, 0, 0)

// ---------------- static device state ----------------
__device__ _Float16 g_hbuf[(size_t)LL * BB * TT * HH];   // h per layer, poisoned each launch
__device__ _Float16 g_xbf[(size_t)BB * TT * II];         // x in f16
__device__ _Float16 g_wih0[G4 * II];
__device__ _Float16 g_whh[(size_t)LL * G4 * HH];
__device__ _Float16 g_wihr[(size_t)3 * G4 * HH];
__device__ float    g_bias[LL * G4];

// ---------------- coherent accessors (compiler-tracked; no inline asm) ----------------
// Retry path: AGENT-scope relaxed atomics (cache-bypassing, guaranteed fresh).
// First-try path: ordinary 16B loads — correctness-safe because every exchange
// location is write-once-per-launch with a deterministic value: any non-poison
// read (cached / stale-valid from prior replay / torn at 4B) IS the final value;
// stale-poison is caught by validation and re-read via the atomic path.
__device__ __forceinline__ u64 ldA64(const void* p) {
  return __hip_atomic_load((const u64*)p, __ATOMIC_RELAXED, __HIP_MEMORY_SCOPE_AGENT);
}
__device__ __forceinline__ void stA32(void* p, unsigned v) {
  __hip_atomic_store((unsigned*)p, v, __ATOMIC_RELAXED, __HIP_MEMORY_SCOPE_AGENT);
}
__device__ __forceinline__ int badv(u32x4 v) {   // any poisoned dword?
  return (v[0] == POISON) | (v[1] == POISON) | (v[2] == POISON) | (v[3] == POISON);
}
__device__ __forceinline__ u32x4 reload16(const void* p) {  // coherent 16B via 2x b64
  u64 lo = ldA64(p), hi = ldA64((const char*)p + 8);
  u32x4 v;
  v[0] = (unsigned)lo; v[1] = (unsigned)(lo >> 32);
  v[2] = (unsigned)hi; v[3] = (unsigned)(hi >> 32);
  return v;
}

__device__ __forceinline__ float fsig(float x) { return 1.f / (1.f + __expf(-x)); }
__device__ __forceinline__ float ftanh(float x) { return 1.f - 2.f / (__expf(2.f * x) + 1.f); }

// A-fragment read from swizzled LDS tile [32][512] f16 (round-3 proven layout)
__device__ __forceinline__ f16x8 ldsA(const _Float16* base, int mt, int kt, int lane) {
  int row = mt * 16 + (lane & 15);
  int off = (row << 10) + (kt << 6) + ((lane >> 4) << 4);
  off ^= (lane & 15) << 4;
  return *(const f16x8*)((const char*)base + off);
}

// ---------------- prep: conversions, bias sums, h-buffer poison ----------------
__device__ __forceinline__ void cv4(_Float16* d, const float* s, size_t n4, size_t tid, size_t stride) {
  for (size_t i = tid; i < n4; i += stride) {
    f32x4v v = ((const f32x4v*)s)[i];
    ((f16x4*)d)[i] = __builtin_convertvector(v, f16x4);
  }
}

__global__ void prep_kernel(const float* __restrict__ x, const float* __restrict__ wih0,
                            const float* __restrict__ whh0, const float* __restrict__ bih0,
                            const float* __restrict__ bhh0, const float* __restrict__ wihr,
                            const float* __restrict__ whhr, const float* __restrict__ bihr,
                            const float* __restrict__ bhhr) {
  size_t tid = (size_t)blockIdx.x * blockDim.x + threadIdx.x;
  size_t stride = (size_t)gridDim.x * blockDim.x;
  cv4(g_xbf, x, (size_t)BB * TT * II / 4, tid, stride);
  cv4(g_wih0, wih0, (size_t)G4 * II / 4, tid, stride);
  cv4(g_whh, whh0, (size_t)G4 * HH / 4, tid, stride);
  cv4(g_whh + (size_t)G4 * HH, whhr, (size_t)3 * G4 * HH / 4, tid, stride);
  cv4(g_wihr, wihr, (size_t)3 * G4 * HH / 4, tid, stride);
  for (size_t i = tid; i < G4; i += stride) g_bias[i] = bih0[i] + bhh0[i];
  for (size_t i = tid; i < 3 * G4; i += stride) g_bias[G4 + i] = bihr[i] + bhhr[i];
  u32x4 P = {POISON, POISON, POISON, POISON};
  size_t n16 = (size_t)LL * BB * TT * HH * 2 / 16;
  u32x4* hb = (u32x4*)g_hbuf;
  for (size_t i = tid; i < n16; i += stride) hb[i] = P;
}

// ---------------- persistent LSTM kernel (flagless data-poll; 2 barriers/step) ----------------
// 256 blocks x 256 threads, 1 block/CU. group g = bid&7 owns batch rows [32g,32g+32);
// block jc = bid>>3 owns h-cols [16jc,16jc+16).
// Step: issue h+x loads -> x-GEMM -> validate/stage hs -> B1 -> h-GEMM -> publish gbuf
// -> validate/stage xs(t+1) -> B2 -> elementwise + fire-and-forget store.
// B1 guards {xs reuse, gbuf reuse}; B2 guards {gbuf read, xs(t+1) read}.
__global__ __launch_bounds__(256, 1) void lstm_kernel() {
  const int tid = threadIdx.x;
  const int g = blockIdx.x & 7;
  const int jc = blockIdx.x >> 3;
  const int w = tid >> 6;
  const int lane = tid & 63;
  const int col = lane & 15, kg = lane >> 4;
  const int n0 = w * 512 + jc * 16;

  __shared__ _Float16 xs[32 * 512];
  __shared__ _Float16 hs[32 * 512];
  __shared__ float gbuf[4][32 * 17];

  const int eb = tid >> 3;        // elementwise: batch row 0..31
  const int ej = (tid & 7) * 2;   // elementwise: h-col pair

  f16x8 wihf[16], whhf[16];

  // one-time zero-pad of xs byte-cols [32,64) (layer 0's K=16..31)
  if (tid < 64) {
    int row = tid >> 1, half = tid & 1;
    int off = (row << 10) + 32 + (half << 4); off ^= (row & 15) << 4;
    u32x4 z = {0u, 0u, 0u, 0u};
    *(u32x4*)((char*)xs + off) = z;
  }

  for (int l = 0; l < LL; ++l) {
    // ---- per-layer: weight fragments into registers ----
    {
      const _Float16* wb = g_whh + ((size_t)l * G4 + (n0 + col)) * HH + kg * 8;
#pragma unroll
      for (int kt = 0; kt < 16; ++kt) whhf[kt] = *(const f16x8*)(wb + kt * 32);
      if (l == 0) {
        if (kg < 2) wihf[0] = *(const f16x8*)(g_wih0 + (n0 + col) * II + kg * 8);
        else { f16x8 z = {}; wihf[0] = z; }
      } else {
        const _Float16* wi = g_wihr + ((size_t)(l - 1) * G4 + (n0 + col)) * HH + kg * 8;
#pragma unroll
        for (int kt = 0; kt < 16; ++kt) wihf[kt] = *(const f16x8*)(wi + kt * 32);
      }
    }
    const float bias = g_bias[l * G4 + n0 + col];
    float c0 = 0.f, c1 = 0.f;

    const _Float16* xsrc = g_hbuf + ((size_t)(l - 1) * BB + 32 * g) * TT * HH;  // l>0
    _Float16* hdst = g_hbuf + ((size_t)l * BB + 32 * g) * TT * HH;

    // ---- prologue: stage xs(0) ----
    u32x4 vx[8], vx0;
    if (l > 0) {
#pragma unroll
      for (int it = 0; it < 8; ++it) {
        int q = tid + it * 256, row = q >> 6, c16 = q & 63;
        vx[it] = *(const u32x4*)((const char*)(xsrc + (size_t)row * TT * HH) + c16 * 16);
      }
      while (true) {
        int bad = 0;
#pragma unroll
        for (int it = 0; it < 8; ++it) bad |= badv(vx[it]);
        if (!__any(bad)) break;
#pragma unroll
        for (int it = 0; it < 8; ++it) {
          int q = tid + it * 256, row = q >> 6, c16 = q & 63;
          vx[it] = reload16((const char*)(xsrc + (size_t)row * TT * HH) + c16 * 16);
        }
      }
#pragma unroll
      for (int it = 0; it < 8; ++it) {
        int q = tid + it * 256, row = q >> 6, c16 = q & 63;
        int off = (row << 10) + (c16 << 4); off ^= (row & 15) << 4;
        *(u32x4*)((char*)xs + off) = vx[it];
      }
    } else if (tid < 64) {
      int row = tid >> 1, half = tid & 1;
      vx0 = *(const u32x4*)(g_xbf + ((size_t)(32 * g + row) * TT) * II + half * 8);
      int off = (row << 10) + (half << 4); off ^= (row & 15) << 4;
      *(u32x4*)((char*)xs + off) = vx0;
    }
    __syncthreads();   // xs(0) ready

    for (int t = 0; t < TT; ++t) {
      // ---- (2) issue h_{t-1} loads first, then x_{t+1} prefetch (plain 16B) ----
      u32x4 vh[8];
      if (t > 0) {
        const _Float16* sh = hdst + (size_t)(t - 1) * HH;
#pragma unroll
        for (int it = 0; it < 8; ++it) {
          int q = tid + it * 256, row = q >> 6, c16 = q & 63;
          vh[it] = *(const u32x4*)((const char*)(sh + (size_t)row * TT * HH) + c16 * 16);
        }
      }
      if (t + 1 < TT) {
        if (l > 0) {
          const _Float16* sx = xsrc + (size_t)(t + 1) * HH;
#pragma unroll
          for (int it = 0; it < 8; ++it) {
            int q = tid + it * 256, row = q >> 6, c16 = q & 63;
            vx[it] = *(const u32x4*)((const char*)(sx + (size_t)row * TT * HH) + c16 * 16);
          }
        } else if (tid < 64) {
          int row = tid >> 1, half = tid & 1;
          vx0 = *(const u32x4*)(g_xbf + ((size_t)(32 * g + row) * TT + (t + 1)) * II + half * 8);
        }
      }

      // ---- (3) x-GEMM (h + x loads in flight) ----
      f32x4 a0 = {bias, bias, bias, bias}, a1 = a0;
      if (l == 0) {
        a0 = MFMA16(ldsA(xs, 0, 0, lane), wihf[0], a0);
        a1 = MFMA16(ldsA(xs, 1, 0, lane), wihf[0], a1);
      } else {
#pragma unroll
        for (int kt = 0; kt < 16; ++kt) {
          a0 = MFMA16(ldsA(xs, 0, kt, lane), wihf[kt], a0);
          a1 = MFMA16(ldsA(xs, 1, kt, lane), wihf[kt], a1);
        }
      }

      // ---- (4) h: validate (counted wait on vh; vx stays in flight) + stage ----
      if (t > 0) {
        const _Float16* sh = hdst + (size_t)(t - 1) * HH;
        while (true) {
          int bad = 0;
#pragma unroll
          for (int it = 0; it < 8; ++it) bad |= badv(vh[it]);
          if (!__any(bad)) break;
#pragma unroll
          for (int it = 0; it < 8; ++it) {
            int q = tid + it * 256, row = q >> 6, c16 = q & 63;
            vh[it] = reload16((const char*)(sh + (size_t)row * TT * HH) + c16 * 16);
          }
        }
#pragma unroll
        for (int it = 0; it < 8; ++it) {
          int q = tid + it * 256, row = q >> 6, c16 = q & 63;
          int off = (row << 10) + (c16 << 4); off ^= (row & 15) << 4;
          *(u32x4*)((char*)hs + off) = vh[it];
        }
      }
      __syncthreads();   // B1: hs ready; guards xs/gbuf reuse (unconditional)

      // ---- (6) h-GEMM ----
      if (t > 0) {
#pragma unroll
        for (int kt = 0; kt < 16; ++kt) {
          a0 = MFMA16(ldsA(hs, 0, kt, lane), whhf[kt], a0);
          a1 = MFMA16(ldsA(hs, 1, kt, lane), whhf[kt], a1);
        }
      }

      // ---- (7) publish gate tiles ----
#pragma unroll
      for (int r = 0; r < 4; ++r) {
        gbuf[w][(kg * 4 + r) * 17 + col] = a0[r];
        gbuf[w][(16 + kg * 4 + r) * 17 + col] = a1[r];
      }

      // ---- (8) validate + stage xs(t+1) ----
      if (t + 1 < TT) {
        if (l > 0) {
          const _Float16* sx = xsrc + (size_t)(t + 1) * HH;
          while (true) {
            int bad = 0;
#pragma unroll
            for (int it = 0; it < 8; ++it) bad |= badv(vx[it]);
            if (!__any(bad)) break;
#pragma unroll
            for (int it = 0; it < 8; ++it) {
              int q = tid + it * 256, row = q >> 6, c16 = q & 63;
              vx[it] = reload16((const char*)(sx + (size_t)row * TT * HH) + c16 * 16);
            }
          }
#pragma unroll
          for (int it = 0; it < 8; ++it) {
            int q = tid + it * 256, row = q >> 6, c16 = q & 63;
            int off = (row << 10) + (c16 << 4); off ^= (row & 15) << 4;
            *(u32x4*)((char*)xs + off) = vx[it];
          }
        } else if (tid < 64) {
          int row = tid >> 1, half = tid & 1;
          int off = (row << 10) + (half << 4); off ^= (row & 15) << 4;
          *(u32x4*)((char*)xs + off) = vx0;
        }
      }
      __syncthreads();   // B2: gbuf + xs(t+1) ready

      // ---- (10) elementwise cell; fire-and-forget coherent store ----
      {
        int i0 = eb * 17 + ej;
        float i_0 = fsig(gbuf[0][i0]),  i_1 = fsig(gbuf[0][i0 + 1]);
        float f_0 = fsig(gbuf[1][i0]),  f_1 = fsig(gbuf[1][i0 + 1]);
        float t_0 = ftanh(gbuf[2][i0]), t_1 = ftanh(gbuf[2][i0 + 1]);
        float o_0 = fsig(gbuf[3][i0]),  o_1 = fsig(gbuf[3][i0 + 1]);
        c0 = f_0 * c0 + i_0 * t_0;
        c1 = f_1 * c1 + i_1 * t_1;
        float h0 = o_0 * ftanh(c0), h1 = o_1 * ftanh(c1);
        _Float16 hh0 = (_Float16)h0, hh1 = (_Float16)h1;
        unsigned pv = ((unsigned)__builtin_bit_cast(unsigned short, hh1) << 16) |
                      (unsigned)__builtin_bit_cast(unsigned short, hh0);
        stA32(hdst + ((size_t)eb * TT + t) * HH + jc * 16 + ej, pv);
      }
    }
  }
}

// ---------------- FC head ----------------
__global__ void fc_kernel(const float* __restrict__ fcw, const float* __restrict__ fcb,
                          float* __restrict__ out) {
  int b = blockIdx.x, lane = threadIdx.x;
  const _Float16* h = g_hbuf + ((size_t)3 * BB + b) * TT * HH + (size_t)(TT - 1) * HH + lane * 8;
  f16x8 hv = *(const f16x8*)h;
  const float* wp = fcw + lane * 8;
  float s = 0.f;
#pragma unroll
  for (int j = 0; j < 8; ++j) s += (float)hv[j] * wp[j];
#pragma unroll
  for (int off = 32; off; off >>= 1) s += __shfl_down(s, off, 64);
  if (lane == 0) out[b] = 1.f / (1.f + __expf(-(s + fcb[0])));
}

// ---------------- launch ----------------
extern "C" void kernel_launch(void* const* d_in, const int* in_sizes, int n_in,
                              void* d_out, int out_size, void* d_ws, size_t ws_size,
                              hipStream_t stream) {
  const float* x    = (const float*)d_in[0];
  const float* wih0 = (const float*)d_in[1];
  const float* whh0 = (const float*)d_in[2];
  const float* bih0 = (const float*)d_in[3];
  const float* bhh0 = (const float*)d_in[4];
  const float* wihr = (const float*)d_in[5];
  const float* whhr = (const float*)d_in[6];
  const float* bihr = (const float*)d_in[7];
  const float* bhhr = (const float*)d_in[8];
  const float* fcw  = (const float*)d_in[9];
  const float* fcb  = (const float*)d_in[10];

  prep_kernel<<<dim3(1024), dim3(256), 0, stream>>>(x, wih0, whh0, bih0, bhh0,
                                                    wihr, whhr, bihr, bhhr);
  lstm_kernel<<<dim3(256), dim3(256), 0, stream>>>();
  fc_kernel<<<dim3(256), dim3(64), 0, stream>>>(fcw, fcb, (float*)d_out);
}

// Round 13
// 6092.279 us; speedup vs baseline: 1.2757x; 1.2757x over previous
//
#include <hip/hip_runtime.h>

// ---------------- problem constants ----------------
#define BB 256   // batch
#define TT 256   // time steps
#define II 16    // input dim (layer 0)
#define HH 512   // hidden
#define G4 2048  // 4*H
#define LL 4     // layers
#define POISON 0xFFFFFFFFu   // f16 pair = (-NaN,-NaN): unreachable for h = o*tanh(c)

typedef float f32x4 __attribute__((ext_vector_type(4)));
typedef _Float16 f16x8 __attribute__((ext_vector_type(8)));
typedef _Float16 f16x4 __attribute__((ext_vector_type(4)));
typedef float f32x4v __attribute__((ext_vector_type(4)));
typedef unsigned int u32x4 __attribute__((ext_vector_type(4)));
typedef unsigned long long u64;

#define MFMA16(a, b, c) __builtin_amdgcn_mfma_f32_16x16x32_f16((a), (b), (c), 0, 0, 0)

// ---------------- static device state ----------------
__device__ _Float16 g_hbuf[(size_t)LL * BB * TT * HH];   // h per layer, poisoned each launch
__device__ _Float16 g_xbf[(size_t)BB * TT * II];         // x in f16
__device__ _Float16 g_wih0[G4 * II];
__device__ _Float16 g_whh[(size_t)LL * G4 * HH];
__device__ _Float16 g_wihr[(size_t)3 * G4 * HH];
__device__ float    g_bias[LL * G4];

// ---------------- coherent accessors (compiler-tracked; no inline asm loads) ----------------
// ALL exchange traffic bypasses L2 (AGENT-scope atomics): r12 proved any cached read
// of a once-poisoned line can stale-hit forever (L2 not invalidated by remote stores).
__device__ __forceinline__ u64 ldA64(const void* p) {
  return __hip_atomic_load((const u64*)p, __ATOMIC_RELAXED, __HIP_MEMORY_SCOPE_AGENT);
}
__device__ __forceinline__ void stA32(void* p, unsigned v) {
  __hip_atomic_store((unsigned*)p, v, __ATOMIC_RELAXED, __HIP_MEMORY_SCOPE_AGENT);
}
__device__ __forceinline__ int badull(u64 v) {   // any poisoned dword half?
  return ((unsigned)v == POISON) | ((unsigned)(v >> 32) == POISON);
}

// Barrier WITHOUT vmcnt drain (the r11->r13 change): __syncthreads() drains vmcnt(0),
// putting the fire-and-forget store's LLC round-trip on the critical path 3x/step.
// LDS ordering needs only lgkmcnt(0) + s_barrier (HK/m201 pattern): each thread drains
// its own ds_writes; global readiness is owned by the poison-validate protocol, and
// in-flight global loads keep their compiler-inserted counted vmcnt waits at first use.
#define BARRIER() do { asm volatile("s_waitcnt lgkmcnt(0)" ::: "memory"); \
                       __builtin_amdgcn_s_barrier(); } while (0)

__device__ __forceinline__ float fsig(float x) { return 1.f / (1.f + __expf(-x)); }
__device__ __forceinline__ float ftanh(float x) { return 1.f - 2.f / (__expf(2.f * x) + 1.f); }

// A-fragment read from swizzled LDS tile [32][512] f16 (round-3 proven layout)
__device__ __forceinline__ f16x8 ldsA(const _Float16* base, int mt, int kt, int lane) {
  int row = mt * 16 + (lane & 15);
  int off = (row << 10) + (kt << 6) + ((lane >> 4) << 4);
  off ^= (lane & 15) << 4;
  return *(const f16x8*)((const char*)base + off);
}

// ---------------- prep: conversions, bias sums, h-buffer poison ----------------
__device__ __forceinline__ void cv4(_Float16* d, const float* s, size_t n4, size_t tid, size_t stride) {
  for (size_t i = tid; i < n4; i += stride) {
    f32x4v v = ((const f32x4v*)s)[i];
    ((f16x4*)d)[i] = __builtin_convertvector(v, f16x4);
  }
}

__global__ void prep_kernel(const float* __restrict__ x, const float* __restrict__ wih0,
                            const float* __restrict__ whh0, const float* __restrict__ bih0,
                            const float* __restrict__ bhh0, const float* __restrict__ wihr,
                            const float* __restrict__ whhr, const float* __restrict__ bihr,
                            const float* __restrict__ bhhr) {
  size_t tid = (size_t)blockIdx.x * blockDim.x + threadIdx.x;
  size_t stride = (size_t)gridDim.x * blockDim.x;
  cv4(g_xbf, x, (size_t)BB * TT * II / 4, tid, stride);
  cv4(g_wih0, wih0, (size_t)G4 * II / 4, tid, stride);
  cv4(g_whh, whh0, (size_t)G4 * HH / 4, tid, stride);
  cv4(g_whh + (size_t)G4 * HH, whhr, (size_t)3 * G4 * HH / 4, tid, stride);
  cv4(g_wihr, wihr, (size_t)3 * G4 * HH / 4, tid, stride);
  for (size_t i = tid; i < G4; i += stride) g_bias[i] = bih0[i] + bhh0[i];
  for (size_t i = tid; i < 3 * G4; i += stride) g_bias[G4 + i] = bihr[i] + bhhr[i];
  u32x4 P = {POISON, POISON, POISON, POISON};
  size_t n16 = (size_t)LL * BB * TT * HH * 2 / 16;
  u32x4* hb = (u32x4*)g_hbuf;
  for (size_t i = tid; i < n16; i += stride) hb[i] = P;
}

// ---------------- persistent LSTM kernel (flagless data-poll; round-11 structure,
//                  drain-free barriers) ----------------
// 256 blocks x 256 threads, 1 block/CU. group g = bid&7 owns batch rows [32g,32g+32);
// block jc = bid>>3 owns h-cols [16jc,16jc+16). Producers fire-and-forget device-scope
// h stores; consumers validate loaded h/x against POISON per wave and retry.
__global__ __launch_bounds__(256, 1) void lstm_kernel() {
  const int tid = threadIdx.x;
  const int g = blockIdx.x & 7;
  const int jc = blockIdx.x >> 3;
  const int w = tid >> 6;
  const int lane = tid & 63;
  const int col = lane & 15, kg = lane >> 4;
  const int n0 = w * 512 + jc * 16;

  __shared__ _Float16 xs[32 * 512];
  __shared__ _Float16 hs[32 * 512];
  __shared__ float gbuf[4][32 * 17];

  const int eb = tid >> 3;        // elementwise: batch row 0..31
  const int ej = (tid & 7) * 2;   // elementwise: h-col pair

  f16x8 wihf[16], whhf[16];

  // one-time zero-pad of xs byte-cols [32,64) (layer 0's K=16..31)
  if (tid < 64) {
    int row = tid >> 1, half = tid & 1;
    int off = (row << 10) + 32 + (half << 4); off ^= (row & 15) << 4;
    u32x4 z = {0u, 0u, 0u, 0u};
    *(u32x4*)((char*)xs + off) = z;
  }

  for (int l = 0; l < LL; ++l) {
    // ---- per-layer: weight fragments into registers (read-only, plain loads) ----
    {
      const _Float16* wb = g_whh + ((size_t)l * G4 + (n0 + col)) * HH + kg * 8;
#pragma unroll
      for (int kt = 0; kt < 16; ++kt) whhf[kt] = *(const f16x8*)(wb + kt * 32);
      if (l == 0) {
        if (kg < 2) wihf[0] = *(const f16x8*)(g_wih0 + (n0 + col) * II + kg * 8);
        else { f16x8 z = {}; wihf[0] = z; }
      } else {
        const _Float16* wi = g_wihr + ((size_t)(l - 1) * G4 + (n0 + col)) * HH + kg * 8;
#pragma unroll
        for (int kt = 0; kt < 16; ++kt) wihf[kt] = *(const f16x8*)(wi + kt * 32);
      }
    }
    const float bias = g_bias[l * G4 + n0 + col];
    float c0 = 0.f, c1 = 0.f;

    const _Float16* xsrc = g_hbuf + ((size_t)(l - 1) * BB + 32 * g) * TT * HH;  // l>0
    _Float16* hdst = g_hbuf + ((size_t)l * BB + 32 * g) * TT * HH;

    // ---- prologue: issue x_0 loads ----
    u64 vx[16]; u32x4 vx0;
    if (l > 0) {
#pragma unroll
      for (int it = 0; it < 8; ++it) {
        int q = tid + it * 256, row = q >> 6, c16 = q & 63;
        const char* p = (const char*)(xsrc + (size_t)row * TT * HH) + c16 * 16;
        vx[2 * it] = ldA64(p); vx[2 * it + 1] = ldA64(p + 8);
      }
    } else if (tid < 64) {
      int row = tid >> 1, half = tid & 1;
      vx0 = *(const u32x4*)(g_xbf + ((size_t)(32 * g + row) * TT) * II + half * 8);
    }

    for (int t = 0; t < TT; ++t) {
      // ---- A) validate prefetched x (counted wait inserted by compiler), stage xs ----
      if (l > 0) {
        while (true) {
          int bad = 0;
#pragma unroll
          for (int k = 0; k < 16; ++k) bad |= badull(vx[k]);
          if (!__any(bad)) break;
#pragma unroll
          for (int it = 0; it < 8; ++it) {
            int q = tid + it * 256, row = q >> 6, c16 = q & 63;
            const char* p = (const char*)(xsrc + (size_t)t * HH + (size_t)row * TT * HH) + c16 * 16;
            vx[2 * it] = ldA64(p); vx[2 * it + 1] = ldA64(p + 8);
          }
        }
#pragma unroll
        for (int it = 0; it < 8; ++it) {
          int q = tid + it * 256, row = q >> 6, c16 = q & 63;
          int off = (row << 10) + (c16 << 4); off ^= (row & 15) << 4;
          u32x4 v;
          v[0] = (unsigned)vx[2 * it];     v[1] = (unsigned)(vx[2 * it] >> 32);
          v[2] = (unsigned)vx[2 * it + 1]; v[3] = (unsigned)(vx[2 * it + 1] >> 32);
          *(u32x4*)((char*)xs + off) = v;
        }
      } else if (tid < 64) {
        int row = tid >> 1, half = tid & 1;
        int off = (row << 10) + (half << 4); off ^= (row & 15) << 4;
        *(u32x4*)((char*)xs + off) = vx0;
      }
      BARRIER();   // xs ready (no vmcnt drain)

      // ---- B) issue h_{t-1} loads, then x_{t+1} prefetch (both fly under x-GEMM) ----
      u64 vh[16];
      if (t > 0) {
        const _Float16* sh = hdst + (size_t)(t - 1) * HH;
#pragma unroll
        for (int it = 0; it < 8; ++it) {
          int q = tid + it * 256, row = q >> 6, c16 = q & 63;
          const char* p = (const char*)(sh + (size_t)row * TT * HH) + c16 * 16;
          vh[2 * it] = ldA64(p); vh[2 * it + 1] = ldA64(p + 8);
        }
      }
      if (t + 1 < TT) {
        if (l > 0) {
          const _Float16* sx = xsrc + (size_t)(t + 1) * HH;
#pragma unroll
          for (int it = 0; it < 8; ++it) {
            int q = tid + it * 256, row = q >> 6, c16 = q & 63;
            const char* p = (const char*)(sx + (size_t)row * TT * HH) + c16 * 16;
            vx[2 * it] = ldA64(p); vx[2 * it + 1] = ldA64(p + 8);
          }
        } else if (tid < 64) {
          int row = tid >> 1, half = tid & 1;
          vx0 = *(const u32x4*)(g_xbf + ((size_t)(32 * g + row) * TT + (t + 1)) * II + half * 8);
        }
      }

      // ---- C) x-GEMM (h + x-prefetch in flight) ----
      f32x4 a0 = {bias, bias, bias, bias}, a1 = a0;
      if (l == 0) {
        a0 = MFMA16(ldsA(xs, 0, 0, lane), wihf[0], a0);
        a1 = MFMA16(ldsA(xs, 1, 0, lane), wihf[0], a1);
      } else {
#pragma unroll
        for (int kt = 0; kt < 16; ++kt) {
          a0 = MFMA16(ldsA(xs, 0, kt, lane), wihf[kt], a0);
          a1 = MFMA16(ldsA(xs, 1, kt, lane), wihf[kt], a1);
        }
      }

      // ---- D) h: validate (counted wait on vh only; vx stays in flight), stage ----
      if (t > 0) {
        while (true) {
          int bad = 0;
#pragma unroll
          for (int k = 0; k < 16; ++k) bad |= badull(vh[k]);
          if (!__any(bad)) break;
          const _Float16* sh = hdst + (size_t)(t - 1) * HH;
#pragma unroll
          for (int it = 0; it < 8; ++it) {
            int q = tid + it * 256, row = q >> 6, c16 = q & 63;
            const char* p = (const char*)(sh + (size_t)row * TT * HH) + c16 * 16;
            vh[2 * it] = ldA64(p); vh[2 * it + 1] = ldA64(p + 8);
          }
        }
#pragma unroll
        for (int it = 0; it < 8; ++it) {
          int q = tid + it * 256, row = q >> 6, c16 = q & 63;
          int off = (row << 10) + (c16 << 4); off ^= (row & 15) << 4;
          u32x4 v;
          v[0] = (unsigned)vh[2 * it];     v[1] = (unsigned)(vh[2 * it] >> 32);
          v[2] = (unsigned)vh[2 * it + 1]; v[3] = (unsigned)(vh[2 * it + 1] >> 32);
          *(u32x4*)((char*)hs + off) = v;
        }
        BARRIER();   // hs ready (no vmcnt drain)

        // ---- F) h-GEMM ----
#pragma unroll
        for (int kt = 0; kt < 16; ++kt) {
          a0 = MFMA16(ldsA(hs, 0, kt, lane), whhf[kt], a0);
          a1 = MFMA16(ldsA(hs, 1, kt, lane), whhf[kt], a1);
        }
      }

      // ---- G) publish gate tiles ----
#pragma unroll
      for (int r = 0; r < 4; ++r) {
        gbuf[w][(kg * 4 + r) * 17 + col] = a0[r];
        gbuf[w][(16 + kg * 4 + r) * 17 + col] = a1[r];
      }
      BARRIER();   // gbuf ready (no vmcnt drain)

      // ---- H) elementwise cell; fire-and-forget device-scope h store ----
      {
        int i0 = eb * 17 + ej;
        float i_0 = fsig(gbuf[0][i0]),  i_1 = fsig(gbuf[0][i0 + 1]);
        float f_0 = fsig(gbuf[1][i0]),  f_1 = fsig(gbuf[1][i0 + 1]);
        float t_0 = ftanh(gbuf[2][i0]), t_1 = ftanh(gbuf[2][i0 + 1]);
        float o_0 = fsig(gbuf[3][i0]),  o_1 = fsig(gbuf[3][i0 + 1]);
        c0 = f_0 * c0 + i_0 * t_0;
        c1 = f_1 * c1 + i_1 * t_1;
        float h0 = o_0 * ftanh(c0), h1 = o_1 * ftanh(c1);
        _Float16 hh0 = (_Float16)h0, hh1 = (_Float16)h1;
        unsigned pv = ((unsigned)__builtin_bit_cast(unsigned short, hh1) << 16) |
                      (unsigned)__builtin_bit_cast(unsigned short, hh0);
        stA32(hdst + ((size_t)eb * TT + t) * HH + jc * 16 + ej, pv);
      }
      // gbuf reuse is guarded by next iteration's xs BARRIER (A) — all waves pass H
      // before any wave can republish gbuf (G) in step t+1.
    }
  }
}

// ---------------- FC head ----------------
__global__ void fc_kernel(const float* __restrict__ fcw, const float* __restrict__ fcb,
                          float* __restrict__ out) {
  int b = blockIdx.x, lane = threadIdx.x;
  const _Float16* h = g_hbuf + ((size_t)3 * BB + b) * TT * HH + (size_t)(TT - 1) * HH + lane * 8;
  f16x8 hv = *(const f16x8*)h;
  const float* wp = fcw + lane * 8;
  float s = 0.f;
#pragma unroll
  for (int j = 0; j < 8; ++j) s += (float)hv[j] * wp[j];
#pragma unroll
  for (int off = 32; off; off >>= 1) s += __shfl_down(s, off, 64);
  if (lane == 0) out[b] = 1.f / (1.f + __expf(-(s + fcb[0])));
}

// ---------------- launch ----------------
extern "C" void kernel_launch(void* const* d_in, const int* in_sizes, int n_in,
                              void* d_out, int out_size, void* d_ws, size_t ws_size,
                              hipStream_t stream) {
  const float* x    = (const float*)d_in[0];
  const float* wih0 = (const float*)d_in[1];
  const float* whh0 = (const float*)d_in[2];
  const float* bih0 = (const float*)d_in[3];
  const float* bhh0 = (const float*)d_in[4];
  const float* wihr = (const float*)d_in[5];
  const float* whhr = (const float*)d_in[6];
  const float* bihr = (const float*)d_in[7];
  const float* bhhr = (const float*)d_in[8];
  const float* fcw  = (const float*)d_in[9];
  const float* fcb  = (const float*)d_in[10];

  prep_kernel<<<dim3(1024), dim3(256), 0, stream>>>(x, wih0, whh0, bih0, bhh0,
                                                    wihr, whhr, bihr, bhhr);
  lstm_kernel<<<dim3(256), dim3(256), 0, stream>>>();
  fc_kernel<<<dim3(256), dim3(64), 0, stream>>>(fcw, fcb, (float*)d_out);
}

// Round 14
// 4227.914 us; speedup vs baseline: 1.8382x; 1.4410x over previous
//
#include <hip/hip_runtime.h>

// ---------------- problem constants ----------------
#define BB 256   // batch
#define TT 256   // time steps
#define II 16    // input dim (layer 0)
#define HH 512   // hidden
#define G4 2048  // 4*H
#define LL 4     // layers
#define POISON 0xFFFFFFFFu   // f16 pair = (-NaN,-NaN): unreachable for h = o*tanh(c)

typedef float f32x4 __attribute__((ext_vector_type(4)));
typedef _Float16 f16x8 __attribute__((ext_vector_type(8)));
typedef _Float16 f16x4 __attribute__((ext_vector_type(4)));
typedef float f32x4v __attribute__((ext_vector_type(4)));
typedef unsigned int u32x4 __attribute__((ext_vector_type(4)));
typedef unsigned long long u64;

#define MFMA16(a, b, c) __builtin_amdgcn_mfma_f32_16x16x32_f16((a), (b), (c), 0, 0, 0)

// ---------------- static device state ----------------
__device__ _Float16 g_hbuf[(size_t)LL * BB * TT * HH];   // h per layer, poisoned each launch
__device__ _Float16 g_xbf[(size_t)BB * TT * II];         // x in f16
__device__ _Float16 g_wih0[G4 * II];
__device__ _Float16 g_whh[(size_t)LL * G4 * HH];
__device__ _Float16 g_wihr[(size_t)3 * G4 * HH];
__device__ float    g_bias[LL * G4];

// ---------------- coherent accessors ----------------
// Ground-truth path (compiler-tracked): AGENT-scope atomics — LLC, placement-independent.
__device__ __forceinline__ u64 ldA64(const void* p) {
  return __hip_atomic_load((const u64*)p, __ATOMIC_RELAXED, __HIP_MEMORY_SCOPE_AGENT);
}
__device__ __forceinline__ void stA32(void* p, unsigned v) {
  __hip_atomic_store((unsigned*)p, v, __ATOMIC_RELAXED, __HIP_MEMORY_SCOPE_AGENT);
}
__device__ __forceinline__ int badv(u32x4 v) {   // any poisoned dword?
  return (v[0] == POISON) | (v[1] == POISON) | (v[2] == POISON) | (v[3] == POISON);
}
__device__ __forceinline__ u32x4 reload16(const void* p) {  // coherent 16B via 2x b64
  u64 lo = ldA64(p), hi = ldA64((const char*)p + 8);
  u32x4 v;
  v[0] = (unsigned)lo; v[1] = (unsigned)(lo >> 32);
  v[2] = (unsigned)hi; v[3] = (unsigned)(hi >> 32);
  return v;
}

// Fast-path batched load: 8x dwordx4 sc0 (L1-bypass, L2-CACHED) + waitcnt INSIDE the
// same asm block (results genuinely ready at block end — sound by construction;
// early-clobber so outputs can't alias address inputs). base must be wave-uniform.
__device__ __forceinline__ void ld8_sc0(u32x4 r[8], const void* base, const unsigned* offs) {
  asm volatile(
      "global_load_dwordx4 %0, %8, %16 sc0\n\t"
      "global_load_dwordx4 %1, %9, %16 sc0\n\t"
      "global_load_dwordx4 %2, %10, %16 sc0\n\t"
      "global_load_dwordx4 %3, %11, %16 sc0\n\t"
      "global_load_dwordx4 %4, %12, %16 sc0\n\t"
      "global_load_dwordx4 %5, %13, %16 sc0\n\t"
      "global_load_dwordx4 %6, %14, %16 sc0\n\t"
      "global_load_dwordx4 %7, %15, %16 sc0\n\t"
      "s_waitcnt vmcnt(0)"
      : "=&v"(r[0]), "=&v"(r[1]), "=&v"(r[2]), "=&v"(r[3]),
        "=&v"(r[4]), "=&v"(r[5]), "=&v"(r[6]), "=&v"(r[7])
      : "v"(offs[0]), "v"(offs[1]), "v"(offs[2]), "v"(offs[3]),
        "v"(offs[4]), "v"(offs[5]), "v"(offs[6]), "v"(offs[7]),
        "s"(base)
      : "memory");
}

// Barrier without vmcnt drain (LDS ordering only; global readiness owned by protocol)
#define BARRIER() do { asm volatile("s_waitcnt lgkmcnt(0)" ::: "memory"); \
                       __builtin_amdgcn_s_barrier(); } while (0)

__device__ __forceinline__ float fsig(float x) { return 1.f / (1.f + __expf(-x)); }
__device__ __forceinline__ float ftanh(float x) { return 1.f - 2.f / (__expf(2.f * x) + 1.f); }

// A-fragment read from swizzled LDS tile [32][512] f16 (round-3 proven layout)
__device__ __forceinline__ f16x8 ldsA(const _Float16* base, int mt, int kt, int lane) {
  int row = mt * 16 + (lane & 15);
  int off = (row << 10) + (kt << 6) + ((lane >> 4) << 4);
  off ^= (lane & 15) << 4;
  return *(const f16x8*)((const char*)base + off);
}

// ---------------- prep: conversions, bias sums, h-buffer poison ----------------
__device__ __forceinline__ void cv4(_Float16* d, const float* s, size_t n4, size_t tid, size_t stride) {
  for (size_t i = tid; i < n4; i += stride) {
    f32x4v v = ((const f32x4v*)s)[i];
    ((f16x4*)d)[i] = __builtin_convertvector(v, f16x4);
  }
}

__global__ void prep_kernel(const float* __restrict__ x, const float* __restrict__ wih0,
                            const float* __restrict__ whh0, const float* __restrict__ bih0,
                            const float* __restrict__ bhh0, const float* __restrict__ wihr,
                            const float* __restrict__ whhr, const float* __restrict__ bihr,
                            const float* __restrict__ bhhr) {
  size_t tid = (size_t)blockIdx.x * blockDim.x + threadIdx.x;
  size_t stride = (size_t)gridDim.x * blockDim.x;
  cv4(g_xbf, x, (size_t)BB * TT * II / 4, tid, stride);
  cv4(g_wih0, wih0, (size_t)G4 * II / 4, tid, stride);
  cv4(g_whh, whh0, (size_t)G4 * HH / 4, tid, stride);
  cv4(g_whh + (size_t)G4 * HH, whhr, (size_t)3 * G4 * HH / 4, tid, stride);
  cv4(g_wihr, wihr, (size_t)3 * G4 * HH / 4, tid, stride);
  for (size_t i = tid; i < G4; i += stride) g_bias[i] = bih0[i] + bhh0[i];
  for (size_t i = tid; i < 3 * G4; i += stride) g_bias[G4 + i] = bihr[i] + bhhr[i];
  u32x4 P = {POISON, POISON, POISON, POISON};
  size_t n16 = (size_t)LL * BB * TT * HH * 2 / 16;
  u32x4* hb = (u32x4*)g_hbuf;
  for (size_t i = tid; i < n16; i += stride) hb[i] = P;
}

// ---------------- persistent LSTM kernel ----------------
// 256 blocks x 256 threads, 1 block/CU. group g = bid&7 owns batch rows [32g,32g+32);
// block jc = bid>>3 owns h-cols [16jc,16jc+16). Exchange protocol:
//   producer: plain store (updates own-XCD writeback L2 -> same-XCD sc0 readers hit)
//             + agent store (LLC ground truth).
//   consumer: batched sc0 first-try (L2-cached -> ~32x LLC traffic cut when the
//             group is XCD-pure) -> poison-validate -> agent-atomic retry (always
//             correct, any placement).
__global__ __launch_bounds__(256, 1) void lstm_kernel() {
  const int tid = threadIdx.x;
  const int g = blockIdx.x & 7;
  const int jc = blockIdx.x >> 3;
  const int w = tid >> 6;
  const int lane = tid & 63;
  const int col = lane & 15, kg = lane >> 4;
  const int n0 = w * 512 + jc * 16;

  __shared__ _Float16 xs[32 * 512];
  __shared__ _Float16 hs[32 * 512];
  __shared__ float gbuf[4][32 * 17];

  const int eb = tid >> 3;        // elementwise: batch row 0..31
  const int ej = (tid & 7) * 2;   // elementwise: h-col pair

  f16x8 wihf[16], whhf[16];

  // per-thread load offsets (t-independent): chunk it -> row (tid>>6)+4it, c16 tid&63
  unsigned offs[8];
#pragma unroll
  for (int it = 0; it < 8; ++it)
    offs[it] = (unsigned)((((tid >> 6) + 4 * it) * (TT * HH * 2)) + (tid & 63) * 16);

  // one-time zero-pad of xs byte-cols [32,64) (layer 0's K=16..31)
  if (tid < 64) {
    int row = tid >> 1, half = tid & 1;
    int off = (row << 10) + 32 + (half << 4); off ^= (row & 15) << 4;
    u32x4 z = {0u, 0u, 0u, 0u};
    *(u32x4*)((char*)xs + off) = z;
  }

  for (int l = 0; l < LL; ++l) {
    // ---- per-layer: weight fragments into registers (read-only, plain loads) ----
    {
      const _Float16* wb = g_whh + ((size_t)l * G4 + (n0 + col)) * HH + kg * 8;
#pragma unroll
      for (int kt = 0; kt < 16; ++kt) whhf[kt] = *(const f16x8*)(wb + kt * 32);
      if (l == 0) {
        if (kg < 2) wihf[0] = *(const f16x8*)(g_wih0 + (n0 + col) * II + kg * 8);
        else { f16x8 z = {}; wihf[0] = z; }
      } else {
        const _Float16* wi = g_wihr + ((size_t)(l - 1) * G4 + (n0 + col)) * HH + kg * 8;
#pragma unroll
        for (int kt = 0; kt < 16; ++kt) wihf[kt] = *(const f16x8*)(wi + kt * 32);
      }
    }
    const float bias = g_bias[l * G4 + n0 + col];
    float c0 = 0.f, c1 = 0.f;

    const char* xb = (const char*)(g_hbuf + ((size_t)(l - 1) * BB + 32 * g) * TT * HH); // l>0
    _Float16* hdst = g_hbuf + ((size_t)l * BB + 32 * g) * TT * HH;
    const char* hb = (const char*)hdst;

    for (int t = 0; t < TT; ++t) {
      // ---- A) x: batched sc0 load + validate/retry + stage ----
      if (l > 0) {
        u32x4 vx[8];
        const char* base = xb + (size_t)t * 1024;
        ld8_sc0(vx, base, offs);
        while (true) {
          int bad = 0;
#pragma unroll
          for (int it = 0; it < 8; ++it) bad |= badv(vx[it]);
          if (!__any(bad)) break;
#pragma unroll
          for (int it = 0; it < 8; ++it) vx[it] = reload16(base + offs[it]);
        }
#pragma unroll
        for (int it = 0; it < 8; ++it) {
          int q = tid + it * 256, row = q >> 6, c16 = q & 63;
          int off = (row << 10) + (c16 << 4); off ^= (row & 15) << 4;
          *(u32x4*)((char*)xs + off) = vx[it];
        }
      } else if (tid < 64) {
        int row = tid >> 1, half = tid & 1;
        u32x4 vx0 = *(const u32x4*)(g_xbf + ((size_t)(32 * g + row) * TT + t) * II + half * 8);
        int off = (row << 10) + (half << 4); off ^= (row & 15) << 4;
        *(u32x4*)((char*)xs + off) = vx0;
      }
      BARRIER();   // xs ready

      // ---- B) x-GEMM ----
      f32x4 a0 = {bias, bias, bias, bias}, a1 = a0;
      if (l == 0) {
        a0 = MFMA16(ldsA(xs, 0, 0, lane), wihf[0], a0);
        a1 = MFMA16(ldsA(xs, 1, 0, lane), wihf[0], a1);
      } else {
#pragma unroll
        for (int kt = 0; kt < 16; ++kt) {
          a0 = MFMA16(ldsA(xs, 0, kt, lane), wihf[kt], a0);
          a1 = MFMA16(ldsA(xs, 1, kt, lane), wihf[kt], a1);
        }
      }

      // ---- C) h: batched sc0 load + validate/retry + stage, then h-GEMM ----
      if (t > 0) {
        u32x4 vh[8];
        const char* base = hb + (size_t)(t - 1) * 1024;
        ld8_sc0(vh, base, offs);
        while (true) {
          int bad = 0;
#pragma unroll
          for (int it = 0; it < 8; ++it) bad |= badv(vh[it]);
          if (!__any(bad)) break;
#pragma unroll
          for (int it = 0; it < 8; ++it) vh[it] = reload16(base + offs[it]);
        }
#pragma unroll
        for (int it = 0; it < 8; ++it) {
          int q = tid + it * 256, row = q >> 6, c16 = q & 63;
          int off = (row << 10) + (c16 << 4); off ^= (row & 15) << 4;
          *(u32x4*)((char*)hs + off) = vh[it];
        }
        BARRIER();   // hs ready
#pragma unroll
        for (int kt = 0; kt < 16; ++kt) {
          a0 = MFMA16(ldsA(hs, 0, kt, lane), whhf[kt], a0);
          a1 = MFMA16(ldsA(hs, 1, kt, lane), whhf[kt], a1);
        }
      }

      // ---- D) publish gate tiles ----
#pragma unroll
      for (int r = 0; r < 4; ++r) {
        gbuf[w][(kg * 4 + r) * 17 + col] = a0[r];
        gbuf[w][(16 + kg * 4 + r) * 17 + col] = a1[r];
      }
      BARRIER();   // gbuf ready

      // ---- E) elementwise cell; dual fire-and-forget store ----
      {
        int i0 = eb * 17 + ej;
        float i_0 = fsig(gbuf[0][i0]),  i_1 = fsig(gbuf[0][i0 + 1]);
        float f_0 = fsig(gbuf[1][i0]),  f_1 = fsig(gbuf[1][i0 + 1]);
        float t_0 = ftanh(gbuf[2][i0]), t_1 = ftanh(gbuf[2][i0 + 1]);
        float o_0 = fsig(gbuf[3][i0]),  o_1 = fsig(gbuf[3][i0 + 1]);
        c0 = f_0 * c0 + i_0 * t_0;
        c1 = f_1 * c1 + i_1 * t_1;
        float h0 = o_0 * ftanh(c0), h1 = o_1 * ftanh(c1);
        _Float16 hh0 = (_Float16)h0, hh1 = (_Float16)h1;
        unsigned pv = ((unsigned)__builtin_bit_cast(unsigned short, hh1) << 16) |
                      (unsigned)__builtin_bit_cast(unsigned short, hh0);
        unsigned* dst = (unsigned*)(hdst + ((size_t)eb * TT + t) * HH + jc * 16 + ej);
        *(volatile unsigned*)dst = pv;   // plain: lands in own-XCD writeback L2
        stA32(dst, pv);                  // agent: LLC ground truth for retries/FC
      }
      // gbuf reuse guarded by next step's xs BARRIER (all waves passed E first).
    }
  }
}

// ---------------- FC head ----------------
__global__ void fc_kernel(const float* __restrict__ fcw, const float* __restrict__ fcb,
                          float* __restrict__ out) {
  int b = blockIdx.x, lane = threadIdx.x;
  const _Float16* h = g_hbuf + ((size_t)3 * BB + b) * TT * HH + (size_t)(TT - 1) * HH + lane * 8;
  f16x8 hv = *(const f16x8*)h;
  const float* wp = fcw + lane * 8;
  float s = 0.f;
#pragma unroll
  for (int j = 0; j < 8; ++j) s += (float)hv[j] * wp[j];
#pragma unroll
  for (int off = 32; off; off >>= 1) s += __shfl_down(s, off, 64);
  if (lane == 0) out[b] = 1.f / (1.f + __expf(-(s + fcb[0])));
}

// ---------------- launch ----------------
extern "C" void kernel_launch(void* const* d_in, const int* in_sizes, int n_in,
                              void* d_out, int out_size, void* d_ws, size_t ws_size,
                              hipStream_t stream) {
  const float* x    = (const float*)d_in[0];
  const float* wih0 = (const float*)d_in[1];
  const float* whh0 = (const float*)d_in[2];
  const float* bih0 = (const float*)d_in[3];
  const float* bhh0 = (const float*)d_in[4];
  const float* wihr = (const float*)d_in[5];
  const float* whhr = (const float*)d_in[6];
  const float* bihr = (const float*)d_in[7];
  const float* bhhr = (const float*)d_in[8];
  const float* fcw  = (const float*)d_in[9];
  const float* fcb  = (const float*)d_in[10];

  prep_kernel<<<dim3(1024), dim3(256), 0, stream>>>(x, wih0, whh0, bih0, bhh0,
                                                    wihr, whhr, bihr, bhhr);
  lstm_kernel<<<dim3(256), dim3(256), 0, stream>>>();
  fc_kernel<<<dim3(256), dim3(64), 0, stream>>>(fcw, fcb, (float*)d_out);
}